// Round 1
// baseline (251.777 us; speedup 1.0000x reference)
//
#include <hip/hip_runtime.h>

// out[b,o] = x[b,:] @ W_lin[:,o]  +  x[b,:] @ W_nl[o] @ x[b,:]
// Reformulated as one GEMM: out = z' @ Wz', where
//   z'[b, p]      = x[b, p>>5] * x[b, p&31]   for p in [0,1024)   (NL part)
//   z'[b, 1024+i] = x[b, i]                                        (linear part)
//   Wz'[p, o]     = W_nl[o, p>>5, p&31] ; Wz'[1024+i, o] = W_lin[i, o]
// M = 524288, N = 32, K = 1056, computed with v_mfma_f32_16x16x32_bf16.
// A-fragments are synthesized in registers (fp32 product -> bf16), B-fragments
// are pre-rearranged into LDS in exact MFMA fragment order.

typedef __attribute__((ext_vector_type(8))) __bf16 bf16x8;
typedef __attribute__((ext_vector_type(4))) float floatx4;

#define NB     524288
#define NTILES (NB / 16)   // 16-row M-tiles per wave

__global__ __launch_bounds__(256, 2)
void nnode_kernel(const float* __restrict__ x, const float* __restrict__ Wlin,
                  const float* __restrict__ Wnl, float* __restrict__ out) {
    // B-fragment store: frag-row r = (ks*2 + t)*64 + lane, 8 bf16 each.
    // For consuming lane l (quad q=l>>4, col c=l&15), n-tile t:
    //   element j = bf16( W_nl[o = c+16t][i = ks][jj = q*8 + j] )
    __shared__ bf16x8 lds_w[4096];   // 64 KiB

    const int tid = threadIdx.x;

    // ---- prep: rearrange NL weights into MFMA B-fragment order ----
    for (int r = tid; r < 4096; r += 256) {
        const int ks = r >> 7;
        const int t  = (r >> 6) & 1;
        const int ln = r & 63;
        const int o  = (ln & 15) + 16 * t;
        const int q  = ln >> 4;
        const float* src = Wnl + o * 1024 + ks * 32 + q * 8;
        floatx4 a = *(const floatx4*)(src);
        floatx4 b = *(const floatx4*)(src + 4);
        bf16x8 v;
        #pragma unroll
        for (int j = 0; j < 4; ++j) { v[j] = (__bf16)a[j]; v[j + 4] = (__bf16)b[j]; }
        lds_w[r] = v;
    }
    __syncthreads();

    const int lane = tid & 63;
    const int wave = tid >> 6;
    const int q    = lane >> 4;   // quad: selects k-range and C rows
    const int col  = lane & 15;   // A row within tile / output column

    // ---- linear-part B fragments, kept in registers ----
    // B[k = q*8+j][n = col (+16)] = W_lin[k][col(+16)]
    bf16x8 bl0, bl1;
    #pragma unroll
    for (int j = 0; j < 8; ++j) {
        bl0[j] = (__bf16)Wlin[(q * 8 + j) * 32 + col];
        bl1[j] = (__bf16)Wlin[(q * 8 + j) * 32 + col + 16];
    }

    const int wid = blockIdx.x * 4 + wave;
    const int nw  = gridDim.x * 4;

    for (int tile = wid; tile < NTILES; tile += nw) {
        const int b0 = tile << 4;
        const float* xr = x + (size_t)(b0 + col) * 32;

        // full row (static indexing for the fully-unrolled K loop)
        float xf[32];
        #pragma unroll
        for (int c = 0; c < 8; ++c) {
            floatx4 v = *(const floatx4*)(xr + c * 4);
            xf[c * 4 + 0] = v[0]; xf[c * 4 + 1] = v[1];
            xf[c * 4 + 2] = v[2]; xf[c * 4 + 3] = v[3];
        }
        // this lane's 8-element window x[b, q*8 .. q*8+7] (avoids dynamic reg index)
        floatx4 w0 = *(const floatx4*)(xr + q * 8);
        floatx4 w1 = *(const floatx4*)(xr + q * 8 + 4);

        floatx4 acc0 = {0.f, 0.f, 0.f, 0.f};
        floatx4 acc1 = {0.f, 0.f, 0.f, 0.f};

        #pragma unroll
        for (int ks = 0; ks < 32; ++ks) {
            bf16x8 bf0 = lds_w[(ks * 2 + 0) * 64 + lane];
            bf16x8 bf1 = lds_w[(ks * 2 + 1) * 64 + lane];
            const float s = xf[ks];
            bf16x8 af;
            #pragma unroll
            for (int j = 0; j < 4; ++j) {
                af[j]     = (__bf16)(s * w0[j]);
                af[j + 4] = (__bf16)(s * w1[j]);
            }
            acc0 = __builtin_amdgcn_mfma_f32_16x16x32_bf16(af, bf0, acc0, 0, 0, 0);
            acc1 = __builtin_amdgcn_mfma_f32_16x16x32_bf16(af, bf1, acc1, 0, 0, 0);
        }

        // linear tail: A element = x[b, q*8+j] itself
        {
            bf16x8 af;
            #pragma unroll
            for (int j = 0; j < 4; ++j) { af[j] = (__bf16)w0[j]; af[j + 4] = (__bf16)w1[j]; }
            acc0 = __builtin_amdgcn_mfma_f32_16x16x32_bf16(af, bl0, acc0, 0, 0, 0);
            acc1 = __builtin_amdgcn_mfma_f32_16x16x32_bf16(af, bl1, acc1, 0, 0, 0);
        }

        // C/D layout: col = lane&15, row = q*4 + reg
        float* orow = out + (size_t)(b0 + q * 4) * 32 + col;
        #pragma unroll
        for (int r = 0; r < 4; ++r) {
            orow[(size_t)r * 32]      = acc0[r];
            orow[(size_t)r * 32 + 16] = acc1[r];
        }
    }
}

extern "C" void kernel_launch(void* const* d_in, const int* in_sizes, int n_in,
                              void* d_out, int out_size, void* d_ws, size_t ws_size,
                              hipStream_t stream) {
    const float* x    = (const float*)d_in[0];
    const float* Wlin = (const float*)d_in[1];
    const float* Wnl  = (const float*)d_in[2];
    float* out        = (float*)d_out;
    nnode_kernel<<<dim3(512), dim3(256), 0, stream>>>(x, Wlin, Wnl, out);
}

// Round 2
// 202.340 us; speedup vs baseline: 1.2443x; 1.2443x over previous
//
#include <hip/hip_runtime.h>

// out[b,o] = x[b,:] @ W_lin[:,o] + x[b] @ W_nl[o] @ x[b]
// GEMM out = z @ Wz, z[b, 32i+j] = x[b,i]*x[b,j] (K=1024) + linear tail,
// via v_mfma_f32_16x16x32_bf16. K is split 4-ways across the block's waves:
// wave w owns ks in [8w, 8w+8) and keeps its B-fragments in REGISTERS
// (16 x bf16x8 = 64 VGPRs, loaded once; W_nl is L2-resident). The linear
// part uses bf16(W_lin * 0.25) in every wave (exact pow2 scale -> the 4-way
// partial sum reconstructs the full linear term). Partials are reduced via a
// small double-buffered LDS buffer, one barrier per tile.

typedef __attribute__((ext_vector_type(8))) __bf16 bf16x8;
typedef __attribute__((ext_vector_type(4))) float floatx4;
typedef __attribute__((ext_vector_type(2))) float floatx2;

#define NB     524288
#define NTILES (NB / 16)
#define GRID   1024
#define REDW   544           // 16 rows * 34 floats (pad 32->34, keeps 8B align)
#define REDB   (4 * REDW)    // per buffer (4 waves)

__global__ __launch_bounds__(256, 4)
void nnode_kernel(const float* __restrict__ x, const float* __restrict__ Wlin,
                  const float* __restrict__ Wnl, float* __restrict__ out) {
    __shared__ float red[2][REDB];   // 2 * 8.5 KiB = 17 KiB

    const int tid  = threadIdx.x;
    const int wave = tid >> 6;
    const int lane = tid & 63;
    const int q    = lane >> 4;   // quad: selects A k-window / C row group
    const int col  = lane & 15;   // output column / A row

    // ---- B fragments for this wave's 8 ks values, kept in registers ----
    // B[k = q*8+j][n = col+16t] = W_nl[o = col+16t][i = ks][j' = q*8+j]
    bf16x8 bW[8][2];
    #pragma unroll
    for (int kl = 0; kl < 8; ++kl) {
        const int ks = wave * 8 + kl;
        #pragma unroll
        for (int t = 0; t < 2; ++t) {
            const float* src = Wnl + (size_t)(col + 16 * t) * 1024 + ks * 32 + q * 8;
            floatx4 a = *(const floatx4*)(src);
            floatx4 b = *(const floatx4*)(src + 4);
            bf16x8 v;
            #pragma unroll
            for (int j = 0; j < 4; ++j) { v[j] = (__bf16)a[j]; v[j + 4] = (__bf16)b[j]; }
            bW[kl][t] = v;
        }
    }
    // ---- linear-part B fragments, quarter-scaled (all 4 waves add 1/4) ----
    bf16x8 bl0, bl1;
    #pragma unroll
    for (int j = 0; j < 8; ++j) {
        bl0[j] = (__bf16)(0.25f * Wlin[(q * 8 + j) * 32 + col]);
        bl1[j] = (__bf16)(0.25f * Wlin[(q * 8 + j) * 32 + col + 16]);
    }

    int it = 0;
    for (int tile = blockIdx.x; tile < NTILES; tile += GRID, ++it) {
        const int b0 = tile << 4;
        const float* xr = x + (size_t)(b0 + col) * 32;

        // this wave's scalars x[m, 8w..8w+8) and the A window x[m, q*8..q*8+8)
        floatx4 s0 = *(const floatx4*)(xr + wave * 8);
        floatx4 s1 = *(const floatx4*)(xr + wave * 8 + 4);
        floatx4 w0 = *(const floatx4*)(xr + q * 8);
        floatx4 w1 = *(const floatx4*)(xr + q * 8 + 4);

        floatx4 acc0 = {0.f, 0.f, 0.f, 0.f};
        floatx4 acc1 = {0.f, 0.f, 0.f, 0.f};

        // linear tail (quarter-scaled, wave-uniform)
        {
            bf16x8 af;
            #pragma unroll
            for (int j = 0; j < 4; ++j) { af[j] = (__bf16)w0[j]; af[j + 4] = (__bf16)w1[j]; }
            acc0 = __builtin_amdgcn_mfma_f32_16x16x32_bf16(af, bl0, acc0, 0, 0, 0);
            acc1 = __builtin_amdgcn_mfma_f32_16x16x32_bf16(af, bl1, acc1, 0, 0, 0);
        }

        #pragma unroll
        for (int kl = 0; kl < 8; ++kl) {
            const float s = (kl < 4) ? s0[kl] : s1[kl - 4];
            bf16x8 af;
            #pragma unroll
            for (int j = 0; j < 4; ++j) {
                af[j]     = (__bf16)(s * w0[j]);
                af[j + 4] = (__bf16)(s * w1[j]);
            }
            acc0 = __builtin_amdgcn_mfma_f32_16x16x32_bf16(af, bW[kl][0], acc0, 0, 0, 0);
            acc1 = __builtin_amdgcn_mfma_f32_16x16x32_bf16(af, bW[kl][1], acc1, 0, 0, 0);
        }

        // ---- write partials to LDS (C/D: row = q*4+r, col = col(+16)) ----
        float* rp = red[it & 1] + wave * REDW;
        #pragma unroll
        for (int r = 0; r < 4; ++r) {
            rp[(q * 4 + r) * 34 + col]      = acc0[r];
            rp[(q * 4 + r) * 34 + col + 16] = acc1[r];
        }
        __syncthreads();

        // ---- reduce 4 partials; thread tid owns output elems [2*tid, 2*tid+1] ----
        const int row = tid >> 4;
        const int c2  = (tid & 15) * 2;
        const float* rb = red[it & 1];
        floatx2 sum = *(const floatx2*)(rb + row * 34 + c2);
        #pragma unroll
        for (int w = 1; w < 4; ++w) {
            floatx2 p = *(const floatx2*)(rb + w * REDW + row * 34 + c2);
            sum.x += p.x; sum.y += p.y;
        }
        *(floatx2*)(out + (size_t)b0 * 32 + tid * 2) = sum;
        // next tile writes the other buffer; the barrier above orders reuse
    }
}

extern "C" void kernel_launch(void* const* d_in, const int* in_sizes, int n_in,
                              void* d_out, int out_size, void* d_ws, size_t ws_size,
                              hipStream_t stream) {
    const float* x    = (const float*)d_in[0];
    const float* Wlin = (const float*)d_in[1];
    const float* Wnl  = (const float*)d_in[2];
    float* out        = (float*)d_out;
    nnode_kernel<<<dim3(GRID), dim3(256), 0, stream>>>(x, Wlin, Wnl, out);
}